// Round 6
// baseline (79.617 us; speedup 1.0000x reference)
//
#include <hip/hip_runtime.h>
#include <hip/hip_bf16.h>

// out[b,i,j,o] = Y[b*128+i][o] + Y[b*128+j][o] + bias[o]
// where Y[m][o] = sum_h L[m][h] * W[o][h]   (M=1024, O=512, H=512)

typedef float f4 __attribute__((ext_vector_type(4)));

#define BM 32
#define BO 64
#define BK 32
#define LDS_PAD 36   // row stride in floats: 144B, multiple of 16B -> aligned f4

__global__ __launch_bounds__(256) void gemm_lwt(const float* __restrict__ A,
                                                const float* __restrict__ W,
                                                float* __restrict__ Y) {
    __shared__ __align__(16) float As[BM][LDS_PAD];
    __shared__ __align__(16) float Ws[BO][LDS_PAD];

    const int tid = threadIdx.x;
    const int m0 = blockIdx.x * BM;   // gridDim.x = 1024/32 = 32
    const int o0 = blockIdx.y * BO;   // gridDim.y = 512/64  = 8
    const int tm = tid >> 4;          // 0..15 -> rows tm*2+ii
    const int to = tid & 15;          // 0..15 -> cols to+16*jj

    float acc[2][4] = {};

    for (int kt = 0; kt < 512; kt += BK) {
        {
            const int row = tid >> 3;        // 0..31
            const int k4  = tid & 7;
            *(f4*)&As[row][k4 * 4] = *(const f4*)&A[(m0 + row) * 512 + kt + k4 * 4];
        }
        #pragma unroll
        for (int l = 0; l < 2; ++l) {
            const int fid = tid + l * 256;
            const int row = fid >> 3;        // 0..63
            const int k4  = fid & 7;
            *(f4*)&Ws[row][k4 * 4] = *(const f4*)&W[(o0 + row) * 512 + kt + k4 * 4];
        }
        __syncthreads();

        #pragma unroll
        for (int k0 = 0; k0 < BK; k0 += 4) {
            f4 a4[2], w4[4];
            #pragma unroll
            for (int ii = 0; ii < 2; ++ii) a4[ii] = *(const f4*)&As[tm * 2 + ii][k0];
            #pragma unroll
            for (int jj = 0; jj < 4; ++jj) w4[jj] = *(const f4*)&Ws[to + 16 * jj][k0];
            #pragma unroll
            for (int ii = 0; ii < 2; ++ii)
                #pragma unroll
                for (int jj = 0; jj < 4; ++jj)
                    acc[ii][jj] += a4[ii].x * w4[jj].x + a4[ii].y * w4[jj].y +
                                   a4[ii].z * w4[jj].z + a4[ii].w * w4[jj].w;
        }
        __syncthreads();
    }

    #pragma unroll
    for (int ii = 0; ii < 2; ++ii)
        #pragma unroll
        for (int jj = 0; jj < 4; ++jj)
            Y[(m0 + tm * 2 + ii) * 512 + o0 + to + 16 * jj] = acc[ii][jj];
}

// 512 blocks: block = (b, i-tile of 4, j-tile of 64). Hoist 4 bias-folded
// Y[b,i0+ii] rows into registers; per j: 1 f4 read + 4 f4 NT stores (1:4 R:W).
__global__ __launch_bounds__(256) void pair_add(const f4* __restrict__ Y4,
                                                const f4* __restrict__ b4,
                                                f4* __restrict__ out4) {
    const int blk = blockIdx.x;          // 0..511
    const int b   = blk >> 6;            // 0..7
    const int r   = blk & 63;
    const int i0  = (r >> 1) * 4;        // 0,4,...,124
    const int j0  = (r & 1) * 64;        // 0 or 64
    const int t   = threadIdx.x;
    const int o4  = t & 127;             // 0..127
    const int js  = t >> 7;              // 0 or 1

    const f4* __restrict__ Yb = Y4 + b * (128 * 128);
    const f4 bb = b4[o4];

    f4 yi[4];
    #pragma unroll
    for (int ii = 0; ii < 4; ++ii)
        yi[ii] = Yb[(i0 + ii) * 128 + o4] + bb;

    f4* __restrict__ ob = out4 + (size_t)(b * 128 + i0) * (128 * 128);

    #pragma unroll 4
    for (int jj = 0; jj < 32; ++jj) {
        const int j = j0 + jj * 2 + js;
        const f4 yj = Yb[j * 128 + o4];
        #pragma unroll
        for (int ii = 0; ii < 4; ++ii) {
            const f4 v = yi[ii] + yj;
            __builtin_nontemporal_store(v, &ob[(size_t)(ii * 128 + j) * 128 + o4]);
        }
    }
}

extern "C" void kernel_launch(void* const* d_in, const int* in_sizes, int n_in,
                              void* d_out, int out_size, void* d_ws, size_t ws_size,
                              hipStream_t stream) {
    const float* L = (const float*)d_in[0];   // [8,128,512]
    const float* W = (const float*)d_in[1];   // [512,512]
    const float* b = (const float*)d_in[2];   // [512]
    float* out = (float*)d_out;               // [8,128,128,512]
    float* Y   = (float*)d_ws;                // [1024,512] scratch, 2 MiB

    dim3 g1(32, 8);
    gemm_lwt<<<g1, 256, 0, stream>>>(L, W, Y);

    pair_add<<<512, 256, 0, stream>>>((const f4*)Y, (const f4*)b, (f4*)out);
    (void)in_sizes; (void)n_in; (void)out_size; (void)ws_size;
}

// Round 7
// 72.150 us; speedup vs baseline: 1.1035x; 1.1035x over previous
//
#include <hip/hip_runtime.h>
#include <hip/hip_bf16.h>

// out[b,i,j,o] = Y[b*128+i][o] + Y[b*128+j][o] + bias[o]
// where Y[m][o] = sum_h L[m][h] * W[o][h]   (M=1024, O=512, H=512)

typedef float f4    __attribute__((ext_vector_type(4)));
typedef short s8    __attribute__((ext_vector_type(8)));   // 8 bf16 (4 VGPRs)
typedef float f32x4 __attribute__((ext_vector_type(4)));

static __device__ __forceinline__ short bf16_rne(float f) {
    unsigned u = __builtin_bit_cast(unsigned, f);
    u += 0x7FFFu + ((u >> 16) & 1u);
    return (short)(u >> 16);
}

// LDS-free MFMA GEMM: 512 blocks x 4 waves; each wave owns one 16x16 Y-tile.
// Lane l loads its A/B fragments (8 contiguous k-floats each) directly from
// global (L2-resident: L=2MiB, W=1MiB), converts to bf16, MFMAs.
__global__ __launch_bounds__(256) void gemm_mfma(const float* __restrict__ A,
                                                 const float* __restrict__ W,
                                                 float* __restrict__ Y) {
    const int tid = threadIdx.x;
    const int w = tid >> 6;          // wave 0..3
    const int l = tid & 63;
    const int rc = l & 15;           // A-row / B-col / C-col
    const int g  = l >> 4;           // k-group (8 floats each)
    const int m0 = blockIdx.x * 32 + (w >> 1) * 16;   // gridDim.x = 32
    const int o0 = blockIdx.y * 32 + (w & 1) * 16;    // gridDim.y = 16

    const float* __restrict__ ap = A + (m0 + rc) * 512 + g * 8;
    const float* __restrict__ wp = W + (o0 + rc) * 512 + g * 8;

    f32x4 acc = {0.f, 0.f, 0.f, 0.f};

    #pragma unroll 4
    for (int kk = 0; kk < 16; ++kk) {
        const f4 alo = *(const f4*)(ap + kk * 32);
        const f4 ahi = *(const f4*)(ap + kk * 32 + 4);
        const f4 blo = *(const f4*)(wp + kk * 32);
        const f4 bhi = *(const f4*)(wp + kk * 32 + 4);
        s8 af, bf;
        af[0] = bf16_rne(alo.x); af[1] = bf16_rne(alo.y);
        af[2] = bf16_rne(alo.z); af[3] = bf16_rne(alo.w);
        af[4] = bf16_rne(ahi.x); af[5] = bf16_rne(ahi.y);
        af[6] = bf16_rne(ahi.z); af[7] = bf16_rne(ahi.w);
        bf[0] = bf16_rne(blo.x); bf[1] = bf16_rne(blo.y);
        bf[2] = bf16_rne(blo.z); bf[3] = bf16_rne(blo.w);
        bf[4] = bf16_rne(bhi.x); bf[5] = bf16_rne(bhi.y);
        bf[6] = bf16_rne(bhi.z); bf[7] = bf16_rne(bhi.w);
        acc = __builtin_amdgcn_mfma_f32_16x16x32_bf16(af, bf, acc, 0, 0, 0);
    }

    // C/D layout (m89-verified): col = l&15, row = (l>>4)*4 + q
    #pragma unroll
    for (int q = 0; q < 4; ++q)
        Y[(m0 + g * 4 + q) * 512 + o0 + rc] = acc[q];
}

// One block per (b,i): writes out[b,i, 0..127, 0..511] = 256 KB contiguous.
__global__ __launch_bounds__(256) void pair_add(const f4* __restrict__ Y4,
                                                const f4* __restrict__ b4,
                                                f4* __restrict__ out4) {
    const int blk = blockIdx.x;          // b*128 + i, 0..1023
    const int t   = threadIdx.x;
    const int o4  = t & 127;             // 0..127 (128 f4 per row)
    const int jh  = t >> 7;              // 0 or 1

    const f4 yib = Y4[blk * 128 + o4] + b4[o4];
    const f4* __restrict__ Yb = Y4 + (blk >> 7) * (128 * 128);
    f4* __restrict__ orow = out4 + blk * (128 * 128);

    #pragma unroll 4
    for (int j = jh; j < 128; j += 2) {
        const f4 r = yib + Yb[j * 128 + o4];
        __builtin_nontemporal_store(r, &orow[j * 128 + o4]);
    }
}

extern "C" void kernel_launch(void* const* d_in, const int* in_sizes, int n_in,
                              void* d_out, int out_size, void* d_ws, size_t ws_size,
                              hipStream_t stream) {
    const float* L = (const float*)d_in[0];   // [8,128,512]
    const float* W = (const float*)d_in[1];   // [512,512]
    const float* b = (const float*)d_in[2];   // [512]
    float* out = (float*)d_out;               // [8,128,128,512]
    float* Y   = (float*)d_ws;                // [1024,512] scratch, 2 MiB

    gemm_mfma<<<dim3(32, 16), 256, 0, stream>>>(L, W, Y);
    pair_add<<<1024, 256, 0, stream>>>((const f4*)Y, (const f4*)b, (f4*)out);
    (void)in_sizes; (void)n_in; (void)out_size; (void)ws_size;
}